// Round 1
// baseline (647.371 us; speedup 1.0000x reference)
//
#include <hip/hip_runtime.h>
#include <hip/hip_bf16.h>
#include <math.h>

// Problem constants (from reference setup_inputs)
constexpr int B   = 2;
constexpr int P   = 19248;
constexpr int N   = 100;   // TOP_K_CONF
constexpr int K   = 20;    // TOP_K_IOU
constexpr int GD  = 32;    // gauss dim
constexpr int GP  = GD * GD;
constexpr int HP  = 138;   // proto H/W
constexpr int HPP = HP * HP;
constexpr int H   = 550;
constexpr int W   = 550;
constexpr int DM  = 32;    // mask dim
constexpr float EPS = 1e-6f;

// Workspace layout (indices in 4-byte units; int and float regions disjoint)
constexpr int OFS_IDX   = 0;                       // int   [B,N]
constexpr int OFS_SCONF = OFS_IDX   + B * N;       // float [B,N]
constexpr int OFS_SLOC  = OFS_SCONF + B * N;       // float [B,N,4]
constexpr int OFS_SMASK = OFS_SLOC  + B * N * 4;   // float [B,N,32]
constexpr int OFS_G     = OFS_SMASK + B * N * DM;  // float [B,N,1024]
constexpr int OFS_S     = OFS_G     + B * N * GP;  // float [B,N]
constexpr int OFS_IOU   = OFS_S     + B * N;       // float [B,N,N] (upper tri only)
constexpr int OFS_KEEP  = OFS_IOU   + B * N * N;   // int   [B,K]
constexpr int OFS_KLOC  = OFS_KEEP  + B * K;       // float [B,K,4]
constexpr int OFS_KMASK = OFS_KLOC  + B * K * 4;   // float [B,K,32]
constexpr int OFS_KCONF = OFS_KMASK + B * K * DM;  // float [B,K]
constexpr int OFS_FC    = OFS_KCONF + B * K;       // float [B,138,138]
// total ~1.09M 4-byte words (~4.4 MB)

// ---------------------------------------------------------------------------
// Kernel 1: conf softmax + exact stable top-100 per batch (lexicographic
// threshold descent: pass k picks max element lex-below previous pick).
// ---------------------------------------------------------------------------
__global__ __launch_bounds__(1024) void ul_topk_kernel(
    const float* __restrict__ conf, const float* __restrict__ loc,
    const float* __restrict__ mask, float* __restrict__ wsf,
    int* __restrict__ wsi) {
  const int b = blockIdx.x;
  const int t = threadIdx.x;
  constexpr int EPT = (P + 1023) / 1024;  // 19

  float v[EPT];
#pragma unroll
  for (int j = 0; j < EPT; j++) {
    int p = j * 1024 + t;
    if (p < P) {
      float c0 = conf[(b * P + p) * 2 + 0];
      float c1 = conf[(b * P + p) * 2 + 1];
      float m  = fmaxf(c0, c1);
      float e0 = expf(c0 - m), e1 = expf(c1 - m);
      v[j] = e1 / (e0 + e1);  // softmax(...)[1]
    } else {
      v[j] = -1e30f;
    }
  }

  __shared__ float swv[16];
  __shared__ int   swi[16];
  __shared__ float s_bv;
  __shared__ int   s_bi;
  __shared__ float outv[N];
  __shared__ int   outi[N];

  float pv = 1e30f;  // previous pick (value, index); lex order: val desc, idx asc
  int   pi = -1;
  for (int sel = 0; sel < N; sel++) {
    float bv = -1e30f;
    int   bi = 0x7fffffff;
#pragma unroll
    for (int j = 0; j < EPT; j++) {
      int p = j * 1024 + t;
      float val = v[j];
      bool elig = (p < P) && (val < pv || (val == pv && p > pi));
      if (elig && (val > bv || (val == bv && p < bi))) { bv = val; bi = p; }
    }
    // wave (64) reduce, tie-break smaller index
    for (int off = 32; off > 0; off >>= 1) {
      float ov = __shfl_down(bv, off);
      int   oi = __shfl_down(bi, off);
      if (ov > bv || (ov == bv && oi < bi)) { bv = ov; bi = oi; }
    }
    int wid = t >> 6;
    if ((t & 63) == 0) { swv[wid] = bv; swi[wid] = bi; }
    __syncthreads();
    if (t == 0) {
      float fbv = swv[0]; int fbi = swi[0];
      for (int wI = 1; wI < 16; wI++) {
        float ov = swv[wI]; int oi = swi[wI];
        if (ov > fbv || (ov == fbv && oi < fbi)) { fbv = ov; fbi = oi; }
      }
      s_bv = fbv; s_bi = fbi;
      outv[sel] = fbv; outi[sel] = fbi;
    }
    __syncthreads();
    pv = s_bv; pi = s_bi;
  }

  // write sorted conf/idx and gather sorted loc/mask
  for (int q = t; q < N; q += 1024) {
    wsi[OFS_IDX + b * N + q]   = outi[q];
    wsf[OFS_SCONF + b * N + q] = outv[q];
  }
  for (int q = t; q < N * 4; q += 1024) {
    int k = q >> 2, d = q & 3;
    wsf[OFS_SLOC + (b * N + k) * 4 + d] = loc[(b * P + outi[k]) * 4 + d];
  }
  for (int q = t; q < N * DM; q += 1024) {
    int k = q >> 5, d = q & 31;
    wsf[OFS_SMASK + (b * N + k) * DM + d] = mask[(b * P + outi[k]) * DM + d];
  }
}

// ---------------------------------------------------------------------------
// Kernel 2: render 32x32 gaussian per (b,n) + its sum
// ---------------------------------------------------------------------------
__global__ __launch_bounds__(256) void ul_gauss_kernel(float* __restrict__ wsf) {
  const int blk = blockIdx.x;  // b*N + n
  const int t = threadIdx.x;
  const float* l = &wsf[OFS_SLOC + blk * 4];
  const float cx = l[0], cy = l[1], bw = l[2], bh = l[3];
  float* g = &wsf[OFS_G + blk * GP];
  float lsum = 0.0f;
#pragma unroll
  for (int q = 0; q < 4; q++) {
    int pix = t + q * 256;
    int y = pix >> 5, x = pix & 31;
    float dx = ((x + 0.5f) / 32.0f - cx) / (bw + 1e-4f);
    float dy = ((y + 0.5f) / 32.0f - cy) / (bh + 1e-4f);
    float gv = expf(-0.5f * (dx * dx + dy * dy));
    g[pix] = gv;
    lsum += gv;
  }
  for (int off = 32; off > 0; off >>= 1) lsum += __shfl_down(lsum, off);
  __shared__ float sp[4];
  if ((t & 63) == 0) sp[t >> 6] = lsum;
  __syncthreads();
  if (t == 0) wsf[OFS_S + blk] = sp[0] + sp[1] + sp[2] + sp[3];
}

// ---------------------------------------------------------------------------
// Kernel 3: upper-triangle gaussian IoU: iou[b,i,j] for j>i
// ---------------------------------------------------------------------------
__global__ __launch_bounds__(256) void ul_iou_kernel(float* __restrict__ wsf) {
  const int blk = blockIdx.x;
  const int b = blk / N, i = blk % N;
  const int t = threadIdx.x;
  __shared__ float gi[GP];
  __shared__ float sp[4];
  const float* g = &wsf[OFS_G + (b * N) * GP];
#pragma unroll
  for (int q = 0; q < 4; q++) gi[t + q * 256] = g[i * GP + t + q * 256];
  const float si = wsf[OFS_S + b * N + i];
  __syncthreads();
  for (int j = i + 1; j < N; j++) {
    float lsum = 0.0f;
#pragma unroll
    for (int q = 0; q < 4; q++) {
      int pix = t + q * 256;
      lsum += fminf(gi[pix], g[j * GP + pix]);
    }
    for (int off = 32; off > 0; off >>= 1) lsum += __shfl_down(lsum, off);
    if ((t & 63) == 0) sp[t >> 6] = lsum;
    __syncthreads();
    if (t == 0) {
      float inter = sp[0] + sp[1] + sp[2] + sp[3];
      float sj = wsf[OFS_S + b * N + j];
      wsf[OFS_IOU + (b * N + i) * N + j] = inter / (si + sj - inter);
    }
    __syncthreads();
  }
}

// ---------------------------------------------------------------------------
// Kernel 4: iou_max, stable bottom-20 keep, gather kept arrays, ae loss
// ---------------------------------------------------------------------------
__global__ __launch_bounds__(128) void ul_select_kernel(
    float* __restrict__ wsf, int* __restrict__ wsi, float* __restrict__ out) {
  const int b = blockIdx.x;
  const int t = threadIdx.x;
  __shared__ float sconf[N];
  __shared__ float ioumax[N];
  __shared__ int   keep[K];
  __shared__ float swv[2];
  __shared__ int   swi[2];
  __shared__ float s_bv;
  __shared__ int   s_bi;

  if (t < N) sconf[t] = wsf[OFS_SCONF + b * N + t];
  if (t < N) {
    float m = 0.0f;  // triu max includes zeros; column 0 -> 0
    for (int i2 = 0; i2 < t; i2++)
      m = fmaxf(m, wsf[OFS_IOU + (b * N + i2) * N + t]);
    ioumax[t] = m;
  }
  __syncthreads();

  // 20 stable passes: min value, tie smaller index (== top_k(-ioumax, 20))
  float pv = -1e30f;
  int   pi = -1;
  for (int sel = 0; sel < K; sel++) {
    float bv = 1e30f;
    int   bi = 0x7fffffff;
    if (t < N) {
      float val = ioumax[t];
      if (val > pv || (val == pv && t > pi)) { bv = val; bi = t; }
    }
    for (int off = 32; off > 0; off >>= 1) {
      float ov = __shfl_down(bv, off);
      int   oi = __shfl_down(bi, off);
      if (ov < bv || (ov == bv && oi < bi)) { bv = ov; bi = oi; }
    }
    if ((t & 63) == 0) { swv[t >> 6] = bv; swi[t >> 6] = bi; }
    __syncthreads();
    if (t == 0) {
      float fbv = swv[0]; int fbi = swi[0];
      if (swv[1] < fbv || (swv[1] == fbv && swi[1] < fbi)) { fbv = swv[1]; fbi = swi[1]; }
      s_bv = fbv; s_bi = fbi;
      keep[sel] = fbi;
    }
    __syncthreads();
    pv = s_bv; pi = s_bi;
  }

  // gather kept loc/mask/conf for variance loss
  for (int q = t; q < K; q += 128) {
    wsi[OFS_KEEP + b * K + q]  = keep[q];
    wsf[OFS_KCONF + b * K + q] = sconf[keep[q]];
  }
  for (int q = t; q < K * 4; q += 128) {
    int k = q >> 2, d = q & 3;
    wsf[OFS_KLOC + (b * K + k) * 4 + d] = wsf[OFS_SLOC + (b * N + keep[k]) * 4 + d];
  }
  for (int q = t; q < K * DM; q += 128) {
    int k = q >> 5, d = q & 31;
    wsf[OFS_KMASK + (b * K + k) * DM + d] = wsf[OFS_SMASK + (b * N + keep[k]) * DM + d];
  }

  // ae loss: sum_k ae_loss[b,k] * sum_{c>r} iou[r,c]*conf_r*conf_c
  float part = 0.0f;
  if (t < K) {
    int r = keep[t];
    float rowsum = 0.0f;
    for (int c = r + 1; c < N; c++)
      rowsum += wsf[OFS_IOU + (b * N + r) * N + c] * sconf[c];
    rowsum *= sconf[r];
    const float* kl = &wsf[OFS_SLOC + (b * N + r) * 4];
    float ael = 0.25f * (kl[0] * kl[0] + kl[1] * kl[1] + kl[2] * kl[2] + kl[3] * kl[3]);
    part = ael * rowsum;
  }
  for (int off = 32; off > 0; off >>= 1) part += __shfl_down(part, off);
  __syncthreads();
  if ((t & 63) == 0) swv[t >> 6] = part;
  __syncthreads();
  if (t == 0) atomicAdd(out + 1, (swv[0] + swv[1]) * (1.0f / (float)(B * N * N)));
}

// ---------------------------------------------------------------------------
// Kernel 5: final_conf [B,138,138]
// ---------------------------------------------------------------------------
__global__ __launch_bounds__(256) void ul_fc_kernel(
    const float* __restrict__ proto, float* __restrict__ wsf) {
  const int b = blockIdx.y;
  const int t = threadIdx.x;
  const int pix = blockIdx.x * 256 + t;
  __shared__ float kl[K * 4];
  __shared__ float kc[K];
  __shared__ float km[K * DM];
  for (int q = t; q < K * 4; q += 256) kl[q] = wsf[OFS_KLOC + b * K * 4 + q];
  for (int q = t; q < K; q += 256) kc[q] = wsf[OFS_KCONF + b * K + q];
  for (int q = t; q < K * DM; q += 256) km[q] = wsf[OFS_KMASK + b * K * DM + q];
  __syncthreads();
  if (pix >= HPP) return;
  const int h = pix / HP, w2 = pix - h * HP;

  float pv[DM];
  const float4* pp = (const float4*)&proto[(size_t)(b * HPP + pix) * DM];
#pragma unroll
  for (int q = 0; q < DM / 4; q++) {
    float4 f = pp[q];
    pv[q * 4 + 0] = f.x; pv[q * 4 + 1] = f.y;
    pv[q * 4 + 2] = f.z; pv[q * 4 + 3] = f.w;
  }
  const float ysv = (h + 0.5f) / 138.0f;
  const float xsv = (w2 + 0.5f) / 138.0f;
  float sum1 = 0.0f, sum2 = 0.0f;
#pragma unroll
  for (int k = 0; k < K; k++) {
    float dot = 0.0f;
#pragma unroll
    for (int d = 0; d < DM; d++) dot += pv[d] * km[k * DM + d];
    float a  = 1.0f / (1.0f + expf(-dot));            // sigmoid(assembled)
    float dx = (xsv - kl[k * 4 + 0]) / (kl[k * 4 + 2] + 1e-4f);
    float dy = (ysv - kl[k * 4 + 1]) / (kl[k * 4 + 3] + 1e-4f);
    float ug = expf(-0.5f * (dx * dx + dy * dy));
    float att = a * ug * kc[k];
    sum1 += att;
    sum2 += att * att;
  }
  float fc = 1.0f - sum2 / (sum1 + EPS);
  if (fc != fc) fc = 0.0f;
  wsf[OFS_FC + b * HPP + pix] = fc;
}

// ---------------------------------------------------------------------------
// Kernel 6: bilinear upsample (half-pixel, edge clamp) + weighted variance
// ---------------------------------------------------------------------------
__global__ __launch_bounds__(256) void ul_var_kernel(
    const float* __restrict__ orig, const float* __restrict__ wsf,
    float* __restrict__ out) {
  const int t = threadIdx.x;
  const int pix = blockIdx.x * 256 + t;
  float acc = 0.0f;
  if (pix < H * W) {
    const int h = pix / W, w2 = pix - h * W;
    const float sc = 138.0f / 550.0f;
    float sy = (h + 0.5f) * sc - 0.5f;
    float sx = (w2 + 0.5f) * sc - 0.5f;
    float fy0 = floorf(sy), fx0 = floorf(sx);
    float wy = sy - fy0, wx = sx - fx0;
    int y0 = max(0, (int)fy0), y1 = min(HP - 1, (int)fy0 + 1);
    int x0 = max(0, (int)fx0), x1 = min(HP - 1, (int)fx0 + 1);
    float r0, r1;
    {
      const float* fc = &wsf[OFS_FC + 0 * HPP];
      float v00 = fc[y0 * HP + x0], v01 = fc[y0 * HP + x1];
      float v10 = fc[y1 * HP + x0], v11 = fc[y1 * HP + x1];
      float top = v00 + (v01 - v00) * wx;
      float bot = v10 + (v11 - v10) * wx;
      r0 = top + (bot - top) * wy;
    }
    {
      const float* fc = &wsf[OFS_FC + 1 * HPP];
      float v00 = fc[y0 * HP + x0], v01 = fc[y0 * HP + x1];
      float v10 = fc[y1 * HP + x0], v11 = fc[y1 * HP + x1];
      float top = v00 + (v01 - v00) * wx;
      float bot = v10 + (v11 - v10) * wx;
      r1 = top + (bot - top) * wy;
    }
    float total = r0 + r1;
    float inv_t = 1.0f / total;           // wmean divides by total (no eps)
    float inv_te = 1.0f / (total + EPS);  // wvar divides by total+eps
#pragma unroll
    for (int c = 0; c < 3; c++) {
      float o0 = orig[((0 * 3 + c) * H + h) * W + w2];
      float o1 = orig[((1 * 3 + c) * H + h) * W + w2];
      float wm = (o0 * r0 + o1 * r1) * inv_t;
      float d0 = o0 - wm, d1 = o1 - wm;
      acc += (d0 * d0 * r0 + d1 * d1 * r1) * inv_te;
    }
  }
  for (int off = 32; off > 0; off >>= 1) acc += __shfl_down(acc, off);
  __shared__ float sp[4];
  if ((t & 63) == 0) sp[t >> 6] = acc;
  __syncthreads();
  if (t == 0)
    atomicAdd(out + 0, (sp[0] + sp[1] + sp[2] + sp[3]) * ((float)B / (float)HP));
}

// ---------------------------------------------------------------------------
extern "C" void kernel_launch(void* const* d_in, const int* in_sizes, int n_in,
                              void* d_out, int out_size, void* d_ws,
                              size_t ws_size, hipStream_t stream) {
  (void)in_sizes; (void)n_in; (void)out_size; (void)ws_size;
  const float* original = (const float*)d_in[0];
  const float* loc      = (const float*)d_in[1];
  const float* conf     = (const float*)d_in[2];
  const float* mask     = (const float*)d_in[3];
  const float* proto    = (const float*)d_in[4];
  float* out = (float*)d_out;
  float* wsf = (float*)d_ws;
  int*   wsi = (int*)d_ws;

  hipMemsetAsync(d_out, 0, 2 * sizeof(float), stream);
  ul_topk_kernel<<<B, 1024, 0, stream>>>(conf, loc, mask, wsf, wsi);
  ul_gauss_kernel<<<B * N, 256, 0, stream>>>(wsf);
  ul_iou_kernel<<<B * N, 256, 0, stream>>>(wsf);
  ul_select_kernel<<<B, 128, 0, stream>>>(wsf, wsi, out);
  ul_fc_kernel<<<dim3((HPP + 255) / 256, B), 256, 0, stream>>>(proto, wsf);
  ul_var_kernel<<<(H * W + 255) / 256, 256, 0, stream>>>(original, wsf, out);
}

// Round 2
// 192.619 us; speedup vs baseline: 3.3609x; 3.3609x over previous
//
#include <hip/hip_runtime.h>
#include <hip/hip_bf16.h>
#include <math.h>

// Problem constants (from reference setup_inputs)
constexpr int B   = 2;
constexpr int P   = 19248;
constexpr int N   = 100;   // TOP_K_CONF
constexpr int K   = 20;    // TOP_K_IOU
constexpr int GD  = 32;    // gauss dim
constexpr int GP  = GD * GD;
constexpr int HP  = 138;   // proto H/W
constexpr int HPP = HP * HP;
constexpr int H   = 550;
constexpr int W   = 550;
constexpr int DM  = 32;    // mask dim
constexpr float EPS = 1e-6f;
constexpr int NBIN = 2048;      // histogram bins over f32 bitpattern >> 19
constexpr int CAND_MAX = 4096;  // per-batch candidate cap (expected ~150)
constexpr int NPAIR = N * (N - 1) / 2;  // 4950

// Workspace layout (4-byte word offsets; int and float regions disjoint)
constexpr int OFS_IDX   = 0;                        // int   [B,N] orig indices of sorted top-100
constexpr int OFS_SCONF = OFS_IDX   + B * N;        // float [B,N]
constexpr int OFS_SLOC  = OFS_SCONF + B * N;        // float [B,N,4]
constexpr int OFS_G     = OFS_SLOC  + B * N * 4;    // float [B,N,1024]
constexpr int OFS_S     = OFS_G     + B * N * GP;   // float [B,N]
constexpr int OFS_IOU   = OFS_S     + B * N;        // float [B,N,N] (upper tri only)
constexpr int OFS_KLOC  = OFS_IOU   + B * N * N;    // float [B,K,4]
constexpr int OFS_KMASK = OFS_KLOC  + B * K * 4;    // float [B,K,32]
constexpr int OFS_KCONF = OFS_KMASK + B * K * DM;   // float [B,K]
constexpr int OFS_FC    = OFS_KCONF + B * K;        // float [B,138,138]
constexpr int OFS_HIST  = OFS_FC    + B * HPP;      // int   [B,2048]  (memset 0)
constexpr int OFS_CCNT  = OFS_HIST  + B * NBIN;     // int   [B]      (memset 0)
constexpr int OFS_T     = OFS_CCNT  + B;            // int   [B]      (memset 0)
constexpr int OFS_CVAL  = OFS_T     + B;            // float [B,CAND_MAX]
constexpr int OFS_CIDX  = OFS_CVAL  + B * CAND_MAX; // int   [B,CAND_MAX]
// total ~287k words (~1.15 MB)

__device__ __forceinline__ float sig_conf(const float* __restrict__ conf, int b, int p) {
  // softmax(conf, axis=2)[:, :, 1] — same max-sub form in hist & compact (bit-identical)
  float c0 = conf[(b * P + p) * 2 + 0];
  float c1 = conf[(b * P + p) * 2 + 1];
  float m  = fmaxf(c0, c1);
  float e0 = expf(c0 - m), e1 = expf(c1 - m);
  return e1 / (e0 + e1);
}

// ---------------------------------------------------------------------------
// Kernel 1: per-batch 2048-bin histogram of sigmoid bitpattern >> 19
// ---------------------------------------------------------------------------
__global__ __launch_bounds__(256) void k_hist(const float* __restrict__ conf,
                                              int* __restrict__ wsi) {
  const int b = blockIdx.y, t = threadIdx.x;
  __shared__ int sh[NBIN];
  for (int q = t; q < NBIN; q += 256) sh[q] = 0;
  __syncthreads();
  const int base = blockIdx.x * 1024;
#pragma unroll
  for (int q = 0; q < 4; q++) {
    int p = base + q * 256 + t;
    if (p < P) {
      float v = sig_conf(conf, b, p);
      atomicAdd(&sh[__float_as_uint(v) >> 19], 1);
    }
  }
  __syncthreads();
  for (int q = t; q < NBIN; q += 256) {
    int c = sh[q];
    if (c) atomicAdd(&wsi[OFS_HIST + b * NBIN + q], c);
  }
}

// ---------------------------------------------------------------------------
// Kernel 2: threshold bin T[b]: smallest bin with cumulative-from-top >= N
// ---------------------------------------------------------------------------
__global__ __launch_bounds__(256) void k_thresh(int* __restrict__ wsi) {
  const int b = blockIdx.x, t = threadIdx.x;
  __shared__ int sh[NBIN];
  for (int q = t; q < NBIN; q += 256) sh[q] = wsi[OFS_HIST + b * NBIN + q];
  __syncthreads();
  if (t == 0) {
    int acc = 0, bin = NBIN - 1;
    for (; bin >= 0; bin--) { acc += sh[bin]; if (acc >= N) break; }
    wsi[OFS_T + b] = bin;
  }
}

// ---------------------------------------------------------------------------
// Kernel 3: compact candidates with bin >= T[b]
// ---------------------------------------------------------------------------
__global__ __launch_bounds__(256) void k_compact(const float* __restrict__ conf,
                                                 float* __restrict__ wsf,
                                                 int* __restrict__ wsi) {
  const int b = blockIdx.y, t = threadIdx.x;
  const int T = wsi[OFS_T + b];
  const int base = blockIdx.x * 1024;
#pragma unroll
  for (int q = 0; q < 4; q++) {
    int p = base + q * 256 + t;
    if (p < P) {
      float v = sig_conf(conf, b, p);
      if ((int)(__float_as_uint(v) >> 19) >= T) {
        int pos = atomicAdd(&wsi[OFS_CCNT + b], 1);
        if (pos < CAND_MAX) {
          wsf[OFS_CVAL + b * CAND_MAX + pos] = v;
          wsi[OFS_CIDX + b * CAND_MAX + pos] = p;
        }
      }
    }
  }
}

// ---------------------------------------------------------------------------
// Kernel 4: exact stable top-100 by ranking candidates (value desc, idx asc),
// then gather sorted conf/idx/loc.
// ---------------------------------------------------------------------------
__global__ __launch_bounds__(1024) void k_rank(const float* __restrict__ loc,
                                               float* __restrict__ wsf,
                                               int* __restrict__ wsi) {
  const int b = blockIdx.x, t = threadIdx.x;
  const int M = min(wsi[OFS_CCNT + b], CAND_MAX);
  constexpr int CPT = CAND_MAX / 1024;  // 4
  __shared__ float tv[1024];
  __shared__ int   ti[1024];
  __shared__ float outv[N];
  __shared__ int   outi[N];

  float mv[CPT]; int mi[CPT]; int rank[CPT];
#pragma unroll
  for (int q = 0; q < CPT; q++) {
    int c = t + q * 1024;
    rank[q] = 0;
    if (c < M) { mv[q] = wsf[OFS_CVAL + b * CAND_MAX + c]; mi[q] = wsi[OFS_CIDX + b * CAND_MAX + c]; }
    else       { mv[q] = -1.0f; mi[q] = -1; }
  }
  for (int tile = 0; tile < M; tile += 1024) {
    int len = min(1024, M - tile);
    __syncthreads();
    if (t < len) { tv[t] = wsf[OFS_CVAL + b * CAND_MAX + tile + t]; ti[t] = wsi[OFS_CIDX + b * CAND_MAX + tile + t]; }
    __syncthreads();
    for (int j = 0; j < len; j++) {
      float jv = tv[j]; int ji = ti[j];
#pragma unroll
      for (int q = 0; q < CPT; q++)
        rank[q] += (jv > mv[q] || (jv == mv[q] && ji < mi[q])) ? 1 : 0;
    }
  }
#pragma unroll
  for (int q = 0; q < CPT; q++) {
    int c = t + q * 1024;
    if (c < M && rank[q] < N) { outv[rank[q]] = mv[q]; outi[rank[q]] = mi[q]; }
  }
  __syncthreads();

  if (t < N) {
    wsi[OFS_IDX + b * N + t]   = outi[t];
    wsf[OFS_SCONF + b * N + t] = outv[t];
  }
  for (int q = t; q < N * 4; q += 1024) {
    int k = q >> 2, d = q & 3;
    wsf[OFS_SLOC + (b * N + k) * 4 + d] = loc[(b * P + outi[k]) * 4 + d];
  }
}

// ---------------------------------------------------------------------------
// Kernel 5: render 32x32 gaussian per (b,n) + its sum
// ---------------------------------------------------------------------------
__global__ __launch_bounds__(256) void ul_gauss_kernel(float* __restrict__ wsf) {
  const int blk = blockIdx.x;  // b*N + n
  const int t = threadIdx.x;
  const float* l = &wsf[OFS_SLOC + blk * 4];
  const float cx = l[0], cy = l[1], bw = l[2], bh = l[3];
  float* g = &wsf[OFS_G + blk * GP];
  float lsum = 0.0f;
#pragma unroll
  for (int q = 0; q < 4; q++) {
    int pix = t + q * 256;
    int y = pix >> 5, x = pix & 31;
    float dx = ((x + 0.5f) / 32.0f - cx) / (bw + 1e-4f);
    float dy = ((y + 0.5f) / 32.0f - cy) / (bh + 1e-4f);
    float gv = expf(-0.5f * (dx * dx + dy * dy));
    g[pix] = gv;
    lsum += gv;
  }
  for (int off = 32; off > 0; off >>= 1) lsum += __shfl_down(lsum, off);
  __shared__ float sp[4];
  if ((t & 63) == 0) sp[t >> 6] = lsum;
  __syncthreads();
  if (t == 0) wsf[OFS_S + blk] = sp[0] + sp[1] + sp[2] + sp[3];
}

// ---------------------------------------------------------------------------
// Kernel 6: gaussian IoU, one block per upper-triangle pair (b, i<j)
// ---------------------------------------------------------------------------
__global__ __launch_bounds__(256) void ul_iou_kernel(float* __restrict__ wsf) {
  const int blk = blockIdx.x;
  const int b = blk / NPAIR;
  const int r = blk - b * NPAIR;
  // decode r -> (i, j), i<j: base(i) = i*(2N-1-i)/2
  int i = (int)((199.0f - sqrtf((float)(39601 - 8 * r))) * 0.5f);
  i = min(max(i, 0), N - 2);
  while (i < N - 2 && ((i + 1) * (2 * N - 2 - i)) / 2 <= r) i++;
  while (i > 0 && (i * (2 * N - 1 - i)) / 2 > r) i--;
  const int j = i + 1 + (r - (i * (2 * N - 1 - i)) / 2);

  const int t = threadIdx.x;
  const float* gi = &wsf[OFS_G + (b * N + i) * GP];
  const float* gj = &wsf[OFS_G + (b * N + j) * GP];
  float lsum = 0.0f;
#pragma unroll
  for (int q = 0; q < 4; q++) {
    int pix = t + q * 256;
    lsum += fminf(gi[pix], gj[pix]);
  }
  for (int off = 32; off > 0; off >>= 1) lsum += __shfl_down(lsum, off);
  __shared__ float sp[4];
  if ((t & 63) == 0) sp[t >> 6] = lsum;
  __syncthreads();
  if (t == 0) {
    float inter = sp[0] + sp[1] + sp[2] + sp[3];
    float si = wsf[OFS_S + b * N + i];
    float sj = wsf[OFS_S + b * N + j];
    wsf[OFS_IOU + (b * N + i) * N + j] = inter / (si + sj - inter);
  }
}

// ---------------------------------------------------------------------------
// Kernel 7: iou_max, stable bottom-20 keep, gather kept arrays, ae loss
// ---------------------------------------------------------------------------
__global__ __launch_bounds__(128) void ul_select_kernel(
    const float* __restrict__ mask, float* __restrict__ wsf,
    int* __restrict__ wsi, float* __restrict__ out) {
  const int b = blockIdx.x;
  const int t = threadIdx.x;
  __shared__ float sconf[N];
  __shared__ float ioumax[N];
  __shared__ int   keep[K];
  __shared__ float swv[2];
  __shared__ int   swi[2];
  __shared__ float s_bv;
  __shared__ int   s_bi;

  if (t < N) sconf[t] = wsf[OFS_SCONF + b * N + t];
  if (t < N) {
    float m = 0.0f;  // triu max includes zeros; column 0 -> 0
    for (int i2 = 0; i2 < t; i2++)
      m = fmaxf(m, wsf[OFS_IOU + (b * N + i2) * N + t]);
    ioumax[t] = m;
  }
  __syncthreads();

  // 20 stable passes: min value, tie smaller index (== top_k(-ioumax, 20))
  float pv = -1e30f;
  int   pi = -1;
  for (int sel = 0; sel < K; sel++) {
    float bv = 1e30f;
    int   bi = 0x7fffffff;
    if (t < N) {
      float val = ioumax[t];
      if (val > pv || (val == pv && t > pi)) { bv = val; bi = t; }
    }
    for (int off = 32; off > 0; off >>= 1) {
      float ov = __shfl_down(bv, off);
      int   oi = __shfl_down(bi, off);
      if (ov < bv || (ov == bv && oi < bi)) { bv = ov; bi = oi; }
    }
    if ((t & 63) == 0) { swv[t >> 6] = bv; swi[t >> 6] = bi; }
    __syncthreads();
    if (t == 0) {
      float fbv = swv[0]; int fbi = swi[0];
      if (swv[1] < fbv || (swv[1] == fbv && swi[1] < fbi)) { fbv = swv[1]; fbi = swi[1]; }
      s_bv = fbv; s_bi = fbi;
      keep[sel] = fbi;
    }
    __syncthreads();
    pv = s_bv; pi = s_bi;
  }

  // gather kept loc/mask/conf for variance loss (mask straight from global)
  for (int q = t; q < K; q += 128)
    wsf[OFS_KCONF + b * K + q] = sconf[keep[q]];
  for (int q = t; q < K * 4; q += 128) {
    int k = q >> 2, d = q & 3;
    wsf[OFS_KLOC + (b * K + k) * 4 + d] = wsf[OFS_SLOC + (b * N + keep[k]) * 4 + d];
  }
  for (int q = t; q < K * DM; q += 128) {
    int k = q >> 5, d = q & 31;
    int orig = wsi[OFS_IDX + b * N + keep[k]];
    wsf[OFS_KMASK + (b * K + k) * DM + d] = mask[(b * P + orig) * DM + d];
  }

  // ae loss: sum_k ae_loss[b,k] * sum_{c>r} iou[r,c]*conf_r*conf_c
  float part = 0.0f;
  if (t < K) {
    int r = keep[t];
    float rowsum = 0.0f;
    for (int c = r + 1; c < N; c++)
      rowsum += wsf[OFS_IOU + (b * N + r) * N + c] * sconf[c];
    rowsum *= sconf[r];
    const float* kl = &wsf[OFS_SLOC + (b * N + r) * 4];
    float ael = 0.25f * (kl[0] * kl[0] + kl[1] * kl[1] + kl[2] * kl[2] + kl[3] * kl[3]);
    part = ael * rowsum;
  }
  for (int off = 32; off > 0; off >>= 1) part += __shfl_down(part, off);
  __syncthreads();
  if ((t & 63) == 0) swv[t >> 6] = part;
  __syncthreads();
  if (t == 0) atomicAdd(out + 1, (swv[0] + swv[1]) * (1.0f / (float)(B * N * N)));
}

// ---------------------------------------------------------------------------
// Kernel 8: final_conf [B,138,138]
// ---------------------------------------------------------------------------
__global__ __launch_bounds__(256) void ul_fc_kernel(
    const float* __restrict__ proto, float* __restrict__ wsf) {
  const int b = blockIdx.y;
  const int t = threadIdx.x;
  const int pix = blockIdx.x * 256 + t;
  __shared__ float kl[K * 4];
  __shared__ float kc[K];
  __shared__ float km[K * DM];
  for (int q = t; q < K * 4; q += 256) kl[q] = wsf[OFS_KLOC + b * K * 4 + q];
  for (int q = t; q < K; q += 256) kc[q] = wsf[OFS_KCONF + b * K + q];
  for (int q = t; q < K * DM; q += 256) km[q] = wsf[OFS_KMASK + b * K * DM + q];
  __syncthreads();
  if (pix >= HPP) return;
  const int h = pix / HP, w2 = pix - h * HP;

  float pv[DM];
  const float4* pp = (const float4*)&proto[(size_t)(b * HPP + pix) * DM];
#pragma unroll
  for (int q = 0; q < DM / 4; q++) {
    float4 f = pp[q];
    pv[q * 4 + 0] = f.x; pv[q * 4 + 1] = f.y;
    pv[q * 4 + 2] = f.z; pv[q * 4 + 3] = f.w;
  }
  const float ysv = (h + 0.5f) / 138.0f;
  const float xsv = (w2 + 0.5f) / 138.0f;
  float sum1 = 0.0f, sum2 = 0.0f;
#pragma unroll
  for (int k = 0; k < K; k++) {
    float dot = 0.0f;
#pragma unroll
    for (int d = 0; d < DM; d++) dot += pv[d] * km[k * DM + d];
    float a  = 1.0f / (1.0f + expf(-dot));            // sigmoid(assembled)
    float dx = (xsv - kl[k * 4 + 0]) / (kl[k * 4 + 2] + 1e-4f);
    float dy = (ysv - kl[k * 4 + 1]) / (kl[k * 4 + 3] + 1e-4f);
    float ug = expf(-0.5f * (dx * dx + dy * dy));
    float att = a * ug * kc[k];
    sum1 += att;
    sum2 += att * att;
  }
  float fc = 1.0f - sum2 / (sum1 + EPS);
  if (fc != fc) fc = 0.0f;
  wsf[OFS_FC + b * HPP + pix] = fc;
}

// ---------------------------------------------------------------------------
// Kernel 9: bilinear upsample (half-pixel, edge clamp) + weighted variance
// ---------------------------------------------------------------------------
__global__ __launch_bounds__(256) void ul_var_kernel(
    const float* __restrict__ orig, const float* __restrict__ wsf,
    float* __restrict__ out) {
  const int t = threadIdx.x;
  const int pix = blockIdx.x * 256 + t;
  float acc = 0.0f;
  if (pix < H * W) {
    const int h = pix / W, w2 = pix - h * W;
    const float sc = 138.0f / 550.0f;
    float sy = (h + 0.5f) * sc - 0.5f;
    float sx = (w2 + 0.5f) * sc - 0.5f;
    float fy0 = floorf(sy), fx0 = floorf(sx);
    float wy = sy - fy0, wx = sx - fx0;
    int y0 = max(0, (int)fy0), y1 = min(HP - 1, (int)fy0 + 1);
    int x0 = max(0, (int)fx0), x1 = min(HP - 1, (int)fx0 + 1);
    float r0, r1;
    {
      const float* fc = &wsf[OFS_FC + 0 * HPP];
      float v00 = fc[y0 * HP + x0], v01 = fc[y0 * HP + x1];
      float v10 = fc[y1 * HP + x0], v11 = fc[y1 * HP + x1];
      float top = v00 + (v01 - v00) * wx;
      float bot = v10 + (v11 - v10) * wx;
      r0 = top + (bot - top) * wy;
    }
    {
      const float* fc = &wsf[OFS_FC + 1 * HPP];
      float v00 = fc[y0 * HP + x0], v01 = fc[y0 * HP + x1];
      float v10 = fc[y1 * HP + x0], v11 = fc[y1 * HP + x1];
      float top = v00 + (v01 - v00) * wx;
      float bot = v10 + (v11 - v10) * wx;
      r1 = top + (bot - top) * wy;
    }
    float total = r0 + r1;
    float inv_t = 1.0f / total;           // wmean divides by total (no eps)
    float inv_te = 1.0f / (total + EPS);  // wvar divides by total+eps
#pragma unroll
    for (int c = 0; c < 3; c++) {
      float o0 = orig[((0 * 3 + c) * H + h) * W + w2];
      float o1 = orig[((1 * 3 + c) * H + h) * W + w2];
      float wm = (o0 * r0 + o1 * r1) * inv_t;
      float d0 = o0 - wm, d1 = o1 - wm;
      acc += (d0 * d0 * r0 + d1 * d1 * r1) * inv_te;
    }
  }
  for (int off = 32; off > 0; off >>= 1) acc += __shfl_down(acc, off);
  __shared__ float sp[4];
  if ((t & 63) == 0) sp[t >> 6] = acc;
  __syncthreads();
  if (t == 0)
    atomicAdd(out + 0, (sp[0] + sp[1] + sp[2] + sp[3]) * ((float)B / (float)HP));
}

// ---------------------------------------------------------------------------
extern "C" void kernel_launch(void* const* d_in, const int* in_sizes, int n_in,
                              void* d_out, int out_size, void* d_ws,
                              size_t ws_size, hipStream_t stream) {
  (void)in_sizes; (void)n_in; (void)out_size; (void)ws_size;
  const float* original = (const float*)d_in[0];
  const float* loc      = (const float*)d_in[1];
  const float* conf     = (const float*)d_in[2];
  const float* mask     = (const float*)d_in[3];
  const float* proto    = (const float*)d_in[4];
  float* out = (float*)d_out;
  float* wsf = (float*)d_ws;
  int*   wsi = (int*)d_ws;

  hipMemsetAsync(d_out, 0, 2 * sizeof(float), stream);
  // zero histogram + candidate counter + threshold (contiguous region)
  hipMemsetAsync(wsi + OFS_HIST, 0, (size_t)(B * NBIN + 2 * B) * sizeof(int), stream);

  const int nblk_p = (P + 1023) / 1024;  // 19
  k_hist<<<dim3(nblk_p, B), 256, 0, stream>>>(conf, wsi);
  k_thresh<<<B, 256, 0, stream>>>(wsi);
  k_compact<<<dim3(nblk_p, B), 256, 0, stream>>>(conf, wsf, wsi);
  k_rank<<<B, 1024, 0, stream>>>(loc, wsf, wsi);
  ul_gauss_kernel<<<B * N, 256, 0, stream>>>(wsf);
  ul_iou_kernel<<<B * NPAIR, 256, 0, stream>>>(wsf);
  ul_select_kernel<<<B, 128, 0, stream>>>(mask, wsf, wsi, out);
  ul_fc_kernel<<<dim3((HPP + 255) / 256, B), 256, 0, stream>>>(proto, wsf);
  ul_var_kernel<<<(H * W + 255) / 256, 256, 0, stream>>>(original, wsf, out);
}

// Round 3
// 156.110 us; speedup vs baseline: 4.1469x; 1.2339x over previous
//
#include <hip/hip_runtime.h>
#include <hip/hip_bf16.h>
#include <math.h>

// Problem constants (from reference setup_inputs)
constexpr int B   = 2;
constexpr int P   = 19248;
constexpr int N   = 100;   // TOP_K_CONF
constexpr int K   = 20;    // TOP_K_IOU
constexpr int GD  = 32;    // gauss dim
constexpr int GP  = GD * GD;
constexpr int HP  = 138;   // proto H/W
constexpr int HPP = HP * HP;
constexpr int H   = 550;
constexpr int W   = 550;
constexpr int DM  = 32;    // mask dim
constexpr float EPS = 1e-6f;
constexpr int NBIN = 2048;      // histogram bins over f32 bitpattern >> 19
constexpr int CAND_MAX = 4096;  // per-batch candidate cap (expected ~150)
constexpr int NPAIR = N * (N - 1) / 2;  // 4950

// Workspace layout (4-byte word offsets; int and float regions disjoint)
constexpr int OFS_IDX   = 0;                        // int   [B,N] orig indices of sorted top-100
constexpr int OFS_SCONF = OFS_IDX   + B * N;        // float [B,N]
constexpr int OFS_SLOC  = OFS_SCONF + B * N;        // float [B,N,4]
constexpr int OFS_G     = OFS_SLOC  + B * N * 4;    // float [B,N,1024]
constexpr int OFS_S     = OFS_G     + B * N * GP;   // float [B,N]
constexpr int OFS_IOU   = OFS_S     + B * N;        // float [B,N,N] (full; lower zeroed by gauss)
constexpr int OFS_KLOC  = OFS_IOU   + B * N * N;    // float [B,K,4]
constexpr int OFS_KMASK = OFS_KLOC  + B * K * 4;    // float [B,K,32]
constexpr int OFS_KCONF = OFS_KMASK + B * K * DM;   // float [B,K]
constexpr int OFS_FC    = OFS_KCONF + B * K;        // float [B,138,138]
constexpr int OFS_HIST  = OFS_FC    + B * HPP;      // int   [B,2048]  (memset 0)
constexpr int OFS_CCNT  = OFS_HIST  + B * NBIN;     // int   [B]      (memset 0)
constexpr int OFS_T     = OFS_CCNT  + B;            // int   [B]      (memset 0)
constexpr int OFS_CVAL  = OFS_T     + B;            // float [B,CAND_MAX]
constexpr int OFS_CIDX  = OFS_CVAL  + B * CAND_MAX; // int   [B,CAND_MAX]
// total ~287k words (~1.15 MB)

__device__ __forceinline__ float sig_conf(const float* __restrict__ conf, int b, int p) {
  // softmax(conf, axis=2)[:, :, 1] — same max-sub form in hist & compact (bit-identical)
  float c0 = conf[(b * P + p) * 2 + 0];
  float c1 = conf[(b * P + p) * 2 + 1];
  float m  = fmaxf(c0, c1);
  float e0 = expf(c0 - m), e1 = expf(c1 - m);
  return e1 / (e0 + e1);
}

// ---------------------------------------------------------------------------
// Kernel 1: per-batch 2048-bin histogram of sigmoid bitpattern >> 19
// (block (0,0) also zero-inits d_out — saves a memset dispatch)
// ---------------------------------------------------------------------------
__global__ __launch_bounds__(256) void k_hist(const float* __restrict__ conf,
                                              int* __restrict__ wsi,
                                              float* __restrict__ out) {
  const int b = blockIdx.y, t = threadIdx.x;
  if (blockIdx.x == 0 && b == 0 && t < 2) out[t] = 0.0f;
  __shared__ int sh[NBIN];
  for (int q = t; q < NBIN; q += 256) sh[q] = 0;
  __syncthreads();
  const int base = blockIdx.x * 1024;
#pragma unroll
  for (int q = 0; q < 4; q++) {
    int p = base + q * 256 + t;
    if (p < P) {
      float v = sig_conf(conf, b, p);
      atomicAdd(&sh[__float_as_uint(v) >> 19], 1);
    }
  }
  __syncthreads();
  for (int q = t; q < NBIN; q += 256) {
    int c = sh[q];
    if (c) atomicAdd(&wsi[OFS_HIST + b * NBIN + q], c);
  }
}

// ---------------------------------------------------------------------------
// Kernel 2: threshold bin T[b]: smallest bin with cumulative-from-top >= N
// ---------------------------------------------------------------------------
__global__ __launch_bounds__(256) void k_thresh(int* __restrict__ wsi) {
  const int b = blockIdx.x, t = threadIdx.x;
  __shared__ int sh[NBIN];
  for (int q = t; q < NBIN; q += 256) sh[q] = wsi[OFS_HIST + b * NBIN + q];
  __syncthreads();
  if (t == 0) {
    int acc = 0, bin = NBIN - 1;
    for (; bin >= 0; bin--) { acc += sh[bin]; if (acc >= N) break; }
    wsi[OFS_T + b] = bin;
  }
}

// ---------------------------------------------------------------------------
// Kernel 3: compact candidates with bin >= T[b]
// ---------------------------------------------------------------------------
__global__ __launch_bounds__(256) void k_compact(const float* __restrict__ conf,
                                                 float* __restrict__ wsf,
                                                 int* __restrict__ wsi) {
  const int b = blockIdx.y, t = threadIdx.x;
  const int T = wsi[OFS_T + b];
  const int base = blockIdx.x * 1024;
#pragma unroll
  for (int q = 0; q < 4; q++) {
    int p = base + q * 256 + t;
    if (p < P) {
      float v = sig_conf(conf, b, p);
      if ((int)(__float_as_uint(v) >> 19) >= T) {
        int pos = atomicAdd(&wsi[OFS_CCNT + b], 1);
        if (pos < CAND_MAX) {
          wsf[OFS_CVAL + b * CAND_MAX + pos] = v;
          wsi[OFS_CIDX + b * CAND_MAX + pos] = p;
        }
      }
    }
  }
}

// ---------------------------------------------------------------------------
// Kernel 4: exact stable top-100 by ranking candidates (value desc, idx asc),
// then gather sorted conf/idx/loc.
// ---------------------------------------------------------------------------
__global__ __launch_bounds__(1024) void k_rank(const float* __restrict__ loc,
                                               float* __restrict__ wsf,
                                               int* __restrict__ wsi) {
  const int b = blockIdx.x, t = threadIdx.x;
  const int M = min(wsi[OFS_CCNT + b], CAND_MAX);
  constexpr int CPT = CAND_MAX / 1024;  // 4
  __shared__ float tv[1024];
  __shared__ int   ti[1024];
  __shared__ float outv[N];
  __shared__ int   outi[N];

  float mv[CPT]; int mi[CPT]; int rank[CPT];
#pragma unroll
  for (int q = 0; q < CPT; q++) {
    int c = t + q * 1024;
    rank[q] = 0;
    if (c < M) { mv[q] = wsf[OFS_CVAL + b * CAND_MAX + c]; mi[q] = wsi[OFS_CIDX + b * CAND_MAX + c]; }
    else       { mv[q] = -1.0f; mi[q] = -1; }
  }
  for (int tile = 0; tile < M; tile += 1024) {
    int len = min(1024, M - tile);
    __syncthreads();
    if (t < len) { tv[t] = wsf[OFS_CVAL + b * CAND_MAX + tile + t]; ti[t] = wsi[OFS_CIDX + b * CAND_MAX + tile + t]; }
    __syncthreads();
    for (int j = 0; j < len; j++) {
      float jv = tv[j]; int ji = ti[j];
#pragma unroll
      for (int q = 0; q < CPT; q++)
        rank[q] += (jv > mv[q] || (jv == mv[q] && ji < mi[q])) ? 1 : 0;
    }
  }
#pragma unroll
  for (int q = 0; q < CPT; q++) {
    int c = t + q * 1024;
    if (c < M && rank[q] < N) { outv[rank[q]] = mv[q]; outi[rank[q]] = mi[q]; }
  }
  __syncthreads();

  if (t < N) {
    wsi[OFS_IDX + b * N + t]   = outi[t];
    wsf[OFS_SCONF + b * N + t] = outv[t];
  }
  for (int q = t; q < N * 4; q += 1024) {
    int k = q >> 2, d = q & 3;
    wsf[OFS_SLOC + (b * N + k) * 4 + d] = loc[(b * P + outi[k]) * 4 + d];
  }
}

// ---------------------------------------------------------------------------
// Kernel 5: render 32x32 gaussian per (b,n) + its sum; also zero-fill
// the lower triangle + diagonal of iou row n (so select can stage full rows)
// ---------------------------------------------------------------------------
__global__ __launch_bounds__(256) void ul_gauss_kernel(float* __restrict__ wsf) {
  const int blk = blockIdx.x;  // b*N + n
  const int t = threadIdx.x;
  const int i = blk % N;
  const float* l = &wsf[OFS_SLOC + blk * 4];
  const float cx = l[0], cy = l[1], bw = l[2], bh = l[3];
  float* g = &wsf[OFS_G + blk * GP];
  float lsum = 0.0f;
#pragma unroll
  for (int q = 0; q < 4; q++) {
    int pix = t + q * 256;
    int y = pix >> 5, x = pix & 31;
    float dx = ((x + 0.5f) / 32.0f - cx) / (bw + 1e-4f);
    float dy = ((y + 0.5f) / 32.0f - cy) / (bh + 1e-4f);
    float gv = expf(-0.5f * (dx * dx + dy * dy));
    g[pix] = gv;
    lsum += gv;
  }
  // zero iou[b, i, 0..i] (lower + diag); upper written by ul_iou_kernel
  for (int q = t; q <= i; q += 256) wsf[OFS_IOU + blk * N + q] = 0.0f;
  for (int off = 32; off > 0; off >>= 1) lsum += __shfl_down(lsum, off);
  __shared__ float sp[4];
  if ((t & 63) == 0) sp[t >> 6] = lsum;
  __syncthreads();
  if (t == 0) wsf[OFS_S + blk] = sp[0] + sp[1] + sp[2] + sp[3];
}

// ---------------------------------------------------------------------------
// Kernel 6: gaussian IoU, one block per upper-triangle pair (b, i<j)
// ---------------------------------------------------------------------------
__global__ __launch_bounds__(256) void ul_iou_kernel(float* __restrict__ wsf) {
  const int blk = blockIdx.x;
  const int b = blk / NPAIR;
  const int r = blk - b * NPAIR;
  // decode r -> (i, j), i<j: base(i) = i*(2N-1-i)/2
  int i = (int)((199.0f - sqrtf((float)(39601 - 8 * r))) * 0.5f);
  i = min(max(i, 0), N - 2);
  while (i < N - 2 && ((i + 1) * (2 * N - 2 - i)) / 2 <= r) i++;
  while (i > 0 && (i * (2 * N - 1 - i)) / 2 > r) i--;
  const int j = i + 1 + (r - (i * (2 * N - 1 - i)) / 2);

  const int t = threadIdx.x;
  const float* gi = &wsf[OFS_G + (b * N + i) * GP];
  const float* gj = &wsf[OFS_G + (b * N + j) * GP];
  float lsum = 0.0f;
#pragma unroll
  for (int q = 0; q < 4; q++) {
    int pix = t + q * 256;
    lsum += fminf(gi[pix], gj[pix]);
  }
  for (int off = 32; off > 0; off >>= 1) lsum += __shfl_down(lsum, off);
  __shared__ float sp[4];
  if ((t & 63) == 0) sp[t >> 6] = lsum;
  __syncthreads();
  if (t == 0) {
    float inter = sp[0] + sp[1] + sp[2] + sp[3];
    float si = wsf[OFS_S + b * N + i];
    float sj = wsf[OFS_S + b * N + j];
    wsf[OFS_IOU + (b * N + i) * N + j] = inter / (si + sj - inter);
  }
}

// ---------------------------------------------------------------------------
// Kernel 7: fully-parallel select: iou staged to LDS, column max via LDS
// atomicMax on bits, rank-based stable bottom-20, gathers, ae loss.
// ---------------------------------------------------------------------------
__global__ __launch_bounds__(1024) void ul_select_kernel(
    const float* __restrict__ mask, float* __restrict__ wsf,
    int* __restrict__ wsi, float* __restrict__ out) {
  const int b = blockIdx.x;
  const int t = threadIdx.x;
  __shared__ float siou[N * N];        // 40 KB
  __shared__ float sconf[N];
  __shared__ unsigned int mbits[N];
  __shared__ int   keep[K];
  __shared__ float coef[K];
  __shared__ float red[16];

  for (int idx = t; idx < N * N; idx += 1024)
    siou[idx] = wsf[OFS_IOU + b * N * N + idx];
  if (t < N) { sconf[t] = wsf[OFS_SCONF + b * N + t]; mbits[t] = 0u; }
  __syncthreads();

  // column max over full column (lower tri is zero == triu semantics; iou>0)
  for (int idx = t; idx < N * N; idx += 1024) {
    int col = idx % N;
    atomicMax(&mbits[col], __float_as_uint(siou[idx]));
  }
  __syncthreads();

  // rank-based stable bottom-K: rank = #{j lex-before (val asc, idx asc)}
  if (t < N) {
    unsigned int vb = mbits[t];
    int rank = 0;
    for (int j = 0; j < N; j++) {
      unsigned int jb = mbits[j];
      rank += (jb < vb || (jb == vb && j < t)) ? 1 : 0;
    }
    if (rank < K) keep[rank] = t;
  }
  __syncthreads();

  if (t < K) {
    int r = keep[t];
    float c = sconf[r];
    wsf[OFS_KCONF + b * K + t] = c;
    const float* kl = &wsf[OFS_SLOC + (b * N + r) * 4];
    float ael = 0.25f * (kl[0] * kl[0] + kl[1] * kl[1] + kl[2] * kl[2] + kl[3] * kl[3]);
    coef[t] = ael * c;  // ae_loss[k] * conf_r
  }
  if (t < K * 4) {
    int k = t >> 2, d = t & 3;
    wsf[OFS_KLOC + (b * K + k) * 4 + d] = wsf[OFS_SLOC + (b * N + keep[k]) * 4 + d];
  }
  if (t < K * DM) {
    int k = t >> 5, d = t & 31;
    int orig = wsi[OFS_IDX + b * N + keep[k]];
    wsf[OFS_KMASK + (b * K + k) * DM + d] = mask[(b * P + orig) * DM + d];
  }
  __syncthreads();

  // ae: sum over (k, c>keep[k]) of iou[r,c] * conf_c * coef[k]
  float acc = 0.0f;
  for (int kc = t; kc < K * N; kc += 1024) {
    int k = kc / N, c = kc - k * N;
    int r = keep[k];
    if (c > r) acc += siou[r * N + c] * sconf[c] * coef[k];
  }
  for (int off = 32; off > 0; off >>= 1) acc += __shfl_down(acc, off);
  if ((t & 63) == 0) red[t >> 6] = acc;
  __syncthreads();
  if (t == 0) {
    float s = 0.0f;
    for (int w2 = 0; w2 < 16; w2++) s += red[w2];
    atomicAdd(out + 1, s * (1.0f / (float)(B * N * N)));
  }
}

// ---------------------------------------------------------------------------
// Kernel 8: final_conf [B,138,138]
// ---------------------------------------------------------------------------
__global__ __launch_bounds__(256) void ul_fc_kernel(
    const float* __restrict__ proto, float* __restrict__ wsf) {
  const int b = blockIdx.y;
  const int t = threadIdx.x;
  const int pix = blockIdx.x * 256 + t;
  __shared__ float kl[K * 4];
  __shared__ float kc[K];
  __shared__ float km[K * DM];
  for (int q = t; q < K * 4; q += 256) kl[q] = wsf[OFS_KLOC + b * K * 4 + q];
  for (int q = t; q < K; q += 256) kc[q] = wsf[OFS_KCONF + b * K + q];
  for (int q = t; q < K * DM; q += 256) km[q] = wsf[OFS_KMASK + b * K * DM + q];
  __syncthreads();
  if (pix >= HPP) return;
  const int h = pix / HP, w2 = pix - h * HP;

  float pv[DM];
  const float4* pp = (const float4*)&proto[(size_t)(b * HPP + pix) * DM];
#pragma unroll
  for (int q = 0; q < DM / 4; q++) {
    float4 f = pp[q];
    pv[q * 4 + 0] = f.x; pv[q * 4 + 1] = f.y;
    pv[q * 4 + 2] = f.z; pv[q * 4 + 3] = f.w;
  }
  const float ysv = (h + 0.5f) / 138.0f;
  const float xsv = (w2 + 0.5f) / 138.0f;
  float sum1 = 0.0f, sum2 = 0.0f;
#pragma unroll
  for (int k = 0; k < K; k++) {
    float dot = 0.0f;
#pragma unroll
    for (int d = 0; d < DM; d++) dot += pv[d] * km[k * DM + d];
    float a  = 1.0f / (1.0f + expf(-dot));            // sigmoid(assembled)
    float dx = (xsv - kl[k * 4 + 0]) / (kl[k * 4 + 2] + 1e-4f);
    float dy = (ysv - kl[k * 4 + 1]) / (kl[k * 4 + 3] + 1e-4f);
    float ug = expf(-0.5f * (dx * dx + dy * dy));
    float att = a * ug * kc[k];
    sum1 += att;
    sum2 += att * att;
  }
  float fc = 1.0f - sum2 / (sum1 + EPS);
  if (fc != fc) fc = 0.0f;
  wsf[OFS_FC + b * HPP + pix] = fc;
}

// ---------------------------------------------------------------------------
// Kernel 9: bilinear upsample (half-pixel, edge clamp) + weighted variance
// ---------------------------------------------------------------------------
__global__ __launch_bounds__(256) void ul_var_kernel(
    const float* __restrict__ orig, const float* __restrict__ wsf,
    float* __restrict__ out) {
  const int t = threadIdx.x;
  const int pix = blockIdx.x * 256 + t;
  float acc = 0.0f;
  if (pix < H * W) {
    const int h = pix / W, w2 = pix - h * W;
    const float sc = 138.0f / 550.0f;
    float sy = (h + 0.5f) * sc - 0.5f;
    float sx = (w2 + 0.5f) * sc - 0.5f;
    float fy0 = floorf(sy), fx0 = floorf(sx);
    float wy = sy - fy0, wx = sx - fx0;
    int y0 = max(0, (int)fy0), y1 = min(HP - 1, (int)fy0 + 1);
    int x0 = max(0, (int)fx0), x1 = min(HP - 1, (int)fx0 + 1);
    float r0, r1;
    {
      const float* fc = &wsf[OFS_FC + 0 * HPP];
      float v00 = fc[y0 * HP + x0], v01 = fc[y0 * HP + x1];
      float v10 = fc[y1 * HP + x0], v11 = fc[y1 * HP + x1];
      float top = v00 + (v01 - v00) * wx;
      float bot = v10 + (v11 - v10) * wx;
      r0 = top + (bot - top) * wy;
    }
    {
      const float* fc = &wsf[OFS_FC + 1 * HPP];
      float v00 = fc[y0 * HP + x0], v01 = fc[y0 * HP + x1];
      float v10 = fc[y1 * HP + x0], v11 = fc[y1 * HP + x1];
      float top = v00 + (v01 - v00) * wx;
      float bot = v10 + (v11 - v10) * wx;
      r1 = top + (bot - top) * wy;
    }
    float total = r0 + r1;
    float inv_t = 1.0f / total;           // wmean divides by total (no eps)
    float inv_te = 1.0f / (total + EPS);  // wvar divides by total+eps
#pragma unroll
    for (int c = 0; c < 3; c++) {
      float o0 = orig[((0 * 3 + c) * H + h) * W + w2];
      float o1 = orig[((1 * 3 + c) * H + h) * W + w2];
      float wm = (o0 * r0 + o1 * r1) * inv_t;
      float d0 = o0 - wm, d1 = o1 - wm;
      acc += (d0 * d0 * r0 + d1 * d1 * r1) * inv_te;
    }
  }
  for (int off = 32; off > 0; off >>= 1) acc += __shfl_down(acc, off);
  __shared__ float sp[4];
  if ((t & 63) == 0) sp[t >> 6] = acc;
  __syncthreads();
  if (t == 0)
    atomicAdd(out + 0, (sp[0] + sp[1] + sp[2] + sp[3]) * ((float)B / (float)HP));
}

// ---------------------------------------------------------------------------
extern "C" void kernel_launch(void* const* d_in, const int* in_sizes, int n_in,
                              void* d_out, int out_size, void* d_ws,
                              size_t ws_size, hipStream_t stream) {
  (void)in_sizes; (void)n_in; (void)out_size; (void)ws_size;
  const float* original = (const float*)d_in[0];
  const float* loc      = (const float*)d_in[1];
  const float* conf     = (const float*)d_in[2];
  const float* mask     = (const float*)d_in[3];
  const float* proto    = (const float*)d_in[4];
  float* out = (float*)d_out;
  float* wsf = (float*)d_ws;
  int*   wsi = (int*)d_ws;

  // zero histogram + candidate counter + threshold (contiguous region)
  hipMemsetAsync(wsi + OFS_HIST, 0, (size_t)(B * NBIN + 2 * B) * sizeof(int), stream);

  const int nblk_p = (P + 1023) / 1024;  // 19
  k_hist<<<dim3(nblk_p, B), 256, 0, stream>>>(conf, wsi, out);
  k_thresh<<<B, 256, 0, stream>>>(wsi);
  k_compact<<<dim3(nblk_p, B), 256, 0, stream>>>(conf, wsf, wsi);
  k_rank<<<B, 1024, 0, stream>>>(loc, wsf, wsi);
  ul_gauss_kernel<<<B * N, 256, 0, stream>>>(wsf);
  ul_iou_kernel<<<B * NPAIR, 256, 0, stream>>>(wsf);
  ul_select_kernel<<<B, 1024, 0, stream>>>(mask, wsf, wsi, out);
  ul_fc_kernel<<<dim3((HPP + 255) / 256, B), 256, 0, stream>>>(proto, wsf);
  ul_var_kernel<<<(H * W + 255) / 256, 256, 0, stream>>>(original, wsf, out);
}

// Round 4
// 134.586 us; speedup vs baseline: 4.8101x; 1.1599x over previous
//
#include <hip/hip_runtime.h>
#include <hip/hip_bf16.h>
#include <math.h>

// Problem constants (from reference setup_inputs)
constexpr int B   = 2;
constexpr int P   = 19248;
constexpr int N   = 100;   // TOP_K_CONF
constexpr int K   = 20;    // TOP_K_IOU
constexpr int GD  = 32;    // gauss dim
constexpr int GP  = GD * GD;
constexpr int HP  = 138;   // proto H/W
constexpr int HPP = HP * HP;
constexpr int H   = 550;
constexpr int W   = 550;
constexpr int DM  = 32;    // mask dim
constexpr float EPS = 1e-6f;
constexpr int NBIN = 2048;      // histogram bins over f32 bitpattern >> 19
constexpr int CAND = 2048;      // candidate cap (expected ~150/batch)
constexpr int NPAIR = N * (N - 1) / 2;  // 4950

// Workspace layout (4-byte word offsets; int and float regions disjoint)
constexpr int OFS_IDX   = 0;                        // int   [B,N] orig indices of sorted top-100
constexpr int OFS_SCONF = OFS_IDX   + B * N;        // float [B,N]
constexpr int OFS_SLOC  = OFS_SCONF + B * N;        // float [B,N,4]
constexpr int OFS_IOU   = OFS_SLOC  + B * N * 4;    // float [B,N,N] (upper tri valid only)
constexpr int OFS_KLOC  = OFS_IOU   + B * N * N;    // float [B,K,4]
constexpr int OFS_KMASK = OFS_KLOC  + B * K * 4;    // float [B,K,32]
constexpr int OFS_KCONF = OFS_KMASK + B * K * DM;   // float [B,K]
constexpr int OFS_FC    = OFS_KCONF + B * K;        // float [B,138,138]
// total ~61k words (~243 KB)

// ---------------------------------------------------------------------------
// Kernel 1: fused exact stable top-100 per batch.
// One block per batch: sigmoid -> LDS histogram -> threshold -> LDS compact
// -> O(M^2) rank (value desc, index asc == lax.top_k stable order) -> gather.
// Block 0 also zero-inits d_out.
// ---------------------------------------------------------------------------
__global__ __launch_bounds__(1024) void k_topk(
    const float* __restrict__ conf, const float* __restrict__ loc,
    float* __restrict__ wsf, int* __restrict__ wsi, float* __restrict__ out) {
  const int b = blockIdx.x;
  const int t = threadIdx.x;
  constexpr int EPT = (P + 1023) / 1024;  // 19
  if (b == 0 && t < 2) out[t] = 0.0f;

  __shared__ int   hist[NBIN];
  __shared__ int   s_T, s_cnt;
  __shared__ float cv[CAND];
  __shared__ int   ci[CAND];
  __shared__ float outv[N];
  __shared__ int   outi[N];

  for (int q = t; q < NBIN; q += 1024) hist[q] = 0;
  if (t == 0) s_cnt = 0;
  __syncthreads();

  // sigmoid (softmax[...,1]) once per element; reused for hist + compact
  float v[EPT];
#pragma unroll
  for (int j = 0; j < EPT; j++) {
    int p = j * 1024 + t;
    if (p < P) {
      float c0 = conf[(b * P + p) * 2 + 0];
      float c1 = conf[(b * P + p) * 2 + 1];
      float m  = fmaxf(c0, c1);
      float e0 = expf(c0 - m), e1 = expf(c1 - m);
      v[j] = e1 / (e0 + e1);
      atomicAdd(&hist[__float_as_uint(v[j]) >> 19], 1);
    } else {
      v[j] = -1.0f;
    }
  }
  __syncthreads();

  // threshold bin: smallest bin with cumulative-from-top >= N
  if (t == 0) {
    int acc = 0, bin = NBIN - 1;
    for (; bin >= 0; bin--) { acc += hist[bin]; if (acc >= N) break; }
    s_T = bin;
  }
  __syncthreads();
  const int T = s_T;

  // compact candidates (bin >= T) into LDS
#pragma unroll
  for (int j = 0; j < EPT; j++) {
    int p = j * 1024 + t;
    if (p < P && (int)(__float_as_uint(v[j]) >> 19) >= T) {
      int pos = atomicAdd(&s_cnt, 1);
      if (pos < CAND) { cv[pos] = v[j]; ci[pos] = p; }
    }
  }
  __syncthreads();
  const int M = min(s_cnt, CAND);

  // rank-based stable top-N: rank = #{j lex-before (val desc, idx asc)}
#pragma unroll
  for (int q = 0; q < CAND / 1024; q++) {
    int c = t + q * 1024;
    if (c < M) {
      float mv = cv[c]; int mi = ci[c];
      int rank = 0;
      for (int j = 0; j < M; j++) {
        float jv = cv[j]; int ji = ci[j];
        rank += (jv > mv || (jv == mv && ji < mi)) ? 1 : 0;
      }
      if (rank < N) { outv[rank] = mv; outi[rank] = mi; }
    }
  }
  __syncthreads();

  if (t < N) {
    wsi[OFS_IDX + b * N + t]   = outi[t];
    wsf[OFS_SCONF + b * N + t] = outv[t];
  }
  if (t < N * 4) {
    int k = t >> 2, d = t & 3;
    wsf[OFS_SLOC + (b * N + k) * 4 + d] = loc[(b * P + outi[k]) * 4 + d];
  }
}

// ---------------------------------------------------------------------------
// Kernel 2: gaussian IoU, one block per upper-triangle pair (b, i<j).
// Gaussians recomputed on the fly (no global g tensor); inter, s_i, s_j
// reduced simultaneously.
// ---------------------------------------------------------------------------
__global__ __launch_bounds__(256) void k_iou(float* __restrict__ wsf) {
  const int blk = blockIdx.x;
  const int b = blk / NPAIR;
  const int r = blk - b * NPAIR;
  // decode r -> (i, j), i<j: base(i) = i*(2N-1-i)/2
  int i = (int)((199.0f - sqrtf((float)(39601 - 8 * r))) * 0.5f);
  i = min(max(i, 0), N - 2);
  while (i < N - 2 && ((i + 1) * (2 * N - 2 - i)) / 2 <= r) i++;
  while (i > 0 && (i * (2 * N - 1 - i)) / 2 > r) i--;
  const int j = i + 1 + (r - (i * (2 * N - 1 - i)) / 2);

  const int t = threadIdx.x;
  const float* li = &wsf[OFS_SLOC + (b * N + i) * 4];
  const float* lj = &wsf[OFS_SLOC + (b * N + j) * 4];
  const float cxi = li[0], cyi = li[1], wi = li[2], hi = li[3];
  const float cxj = lj[0], cyj = lj[1], wj = lj[2], hj = lj[3];

  float smin = 0.0f, ssi = 0.0f, ssj = 0.0f;
#pragma unroll
  for (int q = 0; q < 4; q++) {
    int pix = t + q * 256;
    int y = pix >> 5, x = pix & 31;
    float xs = (x + 0.5f) / 32.0f, ys = (y + 0.5f) / 32.0f;
    float dxi = (xs - cxi) / (wi + 1e-4f);
    float dyi = (ys - cyi) / (hi + 1e-4f);
    float gi = expf(-0.5f * (dxi * dxi + dyi * dyi));
    float dxj = (xs - cxj) / (wj + 1e-4f);
    float dyj = (ys - cyj) / (hj + 1e-4f);
    float gj = expf(-0.5f * (dxj * dxj + dyj * dyj));
    smin += fminf(gi, gj);
    ssi += gi;
    ssj += gj;
  }
  for (int off = 32; off > 0; off >>= 1) {
    smin += __shfl_down(smin, off);
    ssi  += __shfl_down(ssi, off);
    ssj  += __shfl_down(ssj, off);
  }
  __shared__ float sp[3][4];
  if ((t & 63) == 0) {
    int w4 = t >> 6;
    sp[0][w4] = smin; sp[1][w4] = ssi; sp[2][w4] = ssj;
  }
  __syncthreads();
  if (t == 0) {
    float inter = sp[0][0] + sp[0][1] + sp[0][2] + sp[0][3];
    float si    = sp[1][0] + sp[1][1] + sp[1][2] + sp[1][3];
    float sj    = sp[2][0] + sp[2][1] + sp[2][2] + sp[2][3];
    wsf[OFS_IOU + (b * N + i) * N + j] = inter / (si + sj - inter);
  }
}

// ---------------------------------------------------------------------------
// Kernel 3: fully-parallel select: upper-tri iou staged to LDS (lower = 0),
// column max via LDS atomicMax on bits, rank-based stable bottom-20,
// gathers, ae loss.
// ---------------------------------------------------------------------------
__global__ __launch_bounds__(1024) void k_select(
    const float* __restrict__ mask, float* __restrict__ wsf,
    int* __restrict__ wsi, float* __restrict__ out) {
  const int b = blockIdx.x;
  const int t = threadIdx.x;
  __shared__ float siou[N * N];        // 40 KB
  __shared__ float sconf[N];
  __shared__ unsigned int mbits[N];
  __shared__ int   keep[K];
  __shared__ float coef[K];
  __shared__ float red[16];

  for (int idx = t; idx < N * N; idx += 1024) {
    int row = idx / N, col = idx - row * N;
    siou[idx] = (col > row) ? wsf[OFS_IOU + b * N * N + idx] : 0.0f;
  }
  if (t < N) { sconf[t] = wsf[OFS_SCONF + b * N + t]; mbits[t] = 0u; }
  __syncthreads();

  // column max (triu semantics: lower already 0; iou > 0)
  for (int idx = t; idx < N * N; idx += 1024) {
    int col = idx % N;
    atomicMax(&mbits[col], __float_as_uint(siou[idx]));
  }
  __syncthreads();

  // rank-based stable bottom-K: rank = #{j lex-before (val asc, idx asc)}
  if (t < N) {
    unsigned int vb = mbits[t];
    int rank = 0;
    for (int j = 0; j < N; j++) {
      unsigned int jb = mbits[j];
      rank += (jb < vb || (jb == vb && j < t)) ? 1 : 0;
    }
    if (rank < K) keep[rank] = t;
  }
  __syncthreads();

  if (t < K) {
    int r = keep[t];
    float c = sconf[r];
    wsf[OFS_KCONF + b * K + t] = c;
    const float* kl = &wsf[OFS_SLOC + (b * N + r) * 4];
    float ael = 0.25f * (kl[0] * kl[0] + kl[1] * kl[1] + kl[2] * kl[2] + kl[3] * kl[3]);
    coef[t] = ael * c;  // ae_loss[k] * conf_r
  }
  if (t < K * 4) {
    int k = t >> 2, d = t & 3;
    wsf[OFS_KLOC + (b * K + k) * 4 + d] = wsf[OFS_SLOC + (b * N + keep[k]) * 4 + d];
  }
  if (t < K * DM) {
    int k = t >> 5, d = t & 31;
    int orig = wsi[OFS_IDX + b * N + keep[k]];
    wsf[OFS_KMASK + (b * K + k) * DM + d] = mask[(b * P + orig) * DM + d];
  }
  __syncthreads();

  // ae: sum over (k, c>keep[k]) of iou[r,c] * conf_c * coef[k]
  float acc = 0.0f;
  for (int kc = t; kc < K * N; kc += 1024) {
    int k = kc / N, c = kc - k * N;
    int r = keep[k];
    if (c > r) acc += siou[r * N + c] * sconf[c] * coef[k];
  }
  for (int off = 32; off > 0; off >>= 1) acc += __shfl_down(acc, off);
  if ((t & 63) == 0) red[t >> 6] = acc;
  __syncthreads();
  if (t == 0) {
    float s = 0.0f;
    for (int w2 = 0; w2 < 16; w2++) s += red[w2];
    atomicAdd(out + 1, s * (1.0f / (float)(B * N * N)));
  }
}

// ---------------------------------------------------------------------------
// Kernel 4: final_conf [B,138,138]
// ---------------------------------------------------------------------------
__global__ __launch_bounds__(256) void k_fc(
    const float* __restrict__ proto, float* __restrict__ wsf) {
  const int b = blockIdx.y;
  const int t = threadIdx.x;
  const int pix = blockIdx.x * 256 + t;
  __shared__ float kl[K * 4];
  __shared__ float kc[K];
  __shared__ float km[K * DM];
  for (int q = t; q < K * 4; q += 256) kl[q] = wsf[OFS_KLOC + b * K * 4 + q];
  for (int q = t; q < K; q += 256) kc[q] = wsf[OFS_KCONF + b * K + q];
  for (int q = t; q < K * DM; q += 256) km[q] = wsf[OFS_KMASK + b * K * DM + q];
  __syncthreads();
  if (pix >= HPP) return;
  const int h = pix / HP, w2 = pix - h * HP;

  float pv[DM];
  const float4* pp = (const float4*)&proto[(size_t)(b * HPP + pix) * DM];
#pragma unroll
  for (int q = 0; q < DM / 4; q++) {
    float4 f = pp[q];
    pv[q * 4 + 0] = f.x; pv[q * 4 + 1] = f.y;
    pv[q * 4 + 2] = f.z; pv[q * 4 + 3] = f.w;
  }
  const float ysv = (h + 0.5f) / 138.0f;
  const float xsv = (w2 + 0.5f) / 138.0f;
  float sum1 = 0.0f, sum2 = 0.0f;
#pragma unroll
  for (int k = 0; k < K; k++) {
    float dot = 0.0f;
#pragma unroll
    for (int d = 0; d < DM; d++) dot += pv[d] * km[k * DM + d];
    float a  = 1.0f / (1.0f + expf(-dot));            // sigmoid(assembled)
    float dx = (xsv - kl[k * 4 + 0]) / (kl[k * 4 + 2] + 1e-4f);
    float dy = (ysv - kl[k * 4 + 1]) / (kl[k * 4 + 3] + 1e-4f);
    float ug = expf(-0.5f * (dx * dx + dy * dy));
    float att = a * ug * kc[k];
    sum1 += att;
    sum2 += att * att;
  }
  float fc = 1.0f - sum2 / (sum1 + EPS);
  if (fc != fc) fc = 0.0f;
  wsf[OFS_FC + b * HPP + pix] = fc;
}

// ---------------------------------------------------------------------------
// Kernel 5: bilinear upsample (half-pixel, edge clamp) + weighted variance,
// grid-stride (256 blocks) to keep same-address atomics cheap.
// ---------------------------------------------------------------------------
__global__ __launch_bounds__(256) void k_var(
    const float* __restrict__ orig, const float* __restrict__ wsf,
    float* __restrict__ out) {
  const int t = threadIdx.x;
  float acc = 0.0f;
  for (int pix = blockIdx.x * 256 + t; pix < H * W; pix += 256 * 256) {
    const int h = pix / W, w2 = pix - h * W;
    const float sc = 138.0f / 550.0f;
    float sy = (h + 0.5f) * sc - 0.5f;
    float sx = (w2 + 0.5f) * sc - 0.5f;
    float fy0 = floorf(sy), fx0 = floorf(sx);
    float wy = sy - fy0, wx = sx - fx0;
    int y0 = max(0, (int)fy0), y1 = min(HP - 1, (int)fy0 + 1);
    int x0 = max(0, (int)fx0), x1 = min(HP - 1, (int)fx0 + 1);
    float r0, r1;
    {
      const float* fc = &wsf[OFS_FC + 0 * HPP];
      float v00 = fc[y0 * HP + x0], v01 = fc[y0 * HP + x1];
      float v10 = fc[y1 * HP + x0], v11 = fc[y1 * HP + x1];
      float top = v00 + (v01 - v00) * wx;
      float bot = v10 + (v11 - v10) * wx;
      r0 = top + (bot - top) * wy;
    }
    {
      const float* fc = &wsf[OFS_FC + 1 * HPP];
      float v00 = fc[y0 * HP + x0], v01 = fc[y0 * HP + x1];
      float v10 = fc[y1 * HP + x0], v11 = fc[y1 * HP + x1];
      float top = v00 + (v01 - v00) * wx;
      float bot = v10 + (v11 - v10) * wx;
      r1 = top + (bot - top) * wy;
    }
    float total = r0 + r1;
    float inv_t = 1.0f / total;           // wmean divides by total (no eps)
    float inv_te = 1.0f / (total + EPS);  // wvar divides by total+eps
#pragma unroll
    for (int c = 0; c < 3; c++) {
      float o0 = orig[((0 * 3 + c) * H + h) * W + w2];
      float o1 = orig[((1 * 3 + c) * H + h) * W + w2];
      float wm = (o0 * r0 + o1 * r1) * inv_t;
      float d0 = o0 - wm, d1 = o1 - wm;
      acc += (d0 * d0 * r0 + d1 * d1 * r1) * inv_te;
    }
  }
  for (int off = 32; off > 0; off >>= 1) acc += __shfl_down(acc, off);
  __shared__ float sp[4];
  if ((t & 63) == 0) sp[t >> 6] = acc;
  __syncthreads();
  if (t == 0)
    atomicAdd(out + 0, (sp[0] + sp[1] + sp[2] + sp[3]) * ((float)B / (float)HP));
}

// ---------------------------------------------------------------------------
extern "C" void kernel_launch(void* const* d_in, const int* in_sizes, int n_in,
                              void* d_out, int out_size, void* d_ws,
                              size_t ws_size, hipStream_t stream) {
  (void)in_sizes; (void)n_in; (void)out_size; (void)ws_size;
  const float* original = (const float*)d_in[0];
  const float* loc      = (const float*)d_in[1];
  const float* conf     = (const float*)d_in[2];
  const float* mask     = (const float*)d_in[3];
  const float* proto    = (const float*)d_in[4];
  float* out = (float*)d_out;
  float* wsf = (float*)d_ws;
  int*   wsi = (int*)d_ws;

  k_topk<<<B, 1024, 0, stream>>>(conf, loc, wsf, wsi, out);
  k_iou<<<B * NPAIR, 256, 0, stream>>>(wsf);
  k_select<<<B, 1024, 0, stream>>>(mask, wsf, wsi, out);
  k_fc<<<dim3((HPP + 255) / 256, B), 256, 0, stream>>>(proto, wsf);
  k_var<<<256, 256, 0, stream>>>(original, wsf, out);
}